// Round 1
// 801.738 us; speedup vs baseline: 1.0395x; 1.0395x over previous
//
#include <hip/hip_runtime.h>

// Encoder_8718783611479: stateless per-step LSTMCell => one GEMM + elementwise.
//   gates = xt @ W_ih^T (+ b_ih + b_hh), only i,g,o gates live (f * c_prev = 0)
//   out = sigmoid(sigmoid(o_g)*tanh(sigmoid(i_g)*tanh(g_g)))
// xt[b,t,k] = x[b*43200 + k*240 + t]  (K=180 strided, M=t contiguous)
//
// v2: A operand staged in LDS ONCE per block (was: 48 scalar strided global
// loads + sw bf16 cvt, replicated identically in all 6 waves). Coalesced
// float4 loads along t, hw cvt, XOR-swizzled [t][k] bf16 tile, fragments via
// single ds_read_b128 (conflict-free). Double-buffered. Output staged in LDS
// and written as full-line float4 (kills the 1.88x write amplification seen
// in WRITE_SIZE).

#define B_SZ 2048
#define T_SZ 240
#define K_SZ 180
#define H_SZ 90
#define KP   192   // K padded to 6*32
#define TT   16    // t-tile (MFMA M)
#define NT   15    // 240/16

typedef __bf16 bf16x8 __attribute__((ext_vector_type(8)));
typedef float  f32x4  __attribute__((ext_vector_type(4)));

__device__ __forceinline__ float sigmoidf_(float x) {
    return __builtin_amdgcn_rcpf(1.0f + __expf(-x));
}
__device__ __forceinline__ float tanhf_(float x) {
    return 1.0f - 2.0f * __builtin_amdgcn_rcpf(__expf(2.0f * x) + 1.0f);
}

// Swizzled element index into a [TT][KP] bf16 tile.
// element (t,k) -> t*KP + ((k>>3) ^ (t&7))*8 + (k&7)
// Read side: lane(q,n), ks: 8 consecutive k at granule g=ks*4+q, row t=n:
//   base = n*KP + ((g ^ (n&7))<<3)  -> 16B aligned ds_read_b128, conflict-free
//   (bank group 4*((g^(n&7))&7): 8 lanes x 4 dwords = exact 8-phase minimum).
__device__ __forceinline__ int aidx(int t, int k) {
    return t * KP + ((((k >> 3) ^ (t & 7)) << 3) | (k & 7));
}

__global__ __launch_bounds__(384, 4) void lstm_fused_kernel(
    const float* __restrict__ x,
    const float* __restrict__ W_ih,
    const float* __restrict__ b_ih,
    const float* __restrict__ b_hh,
    float* __restrict__ out)
{
    __shared__ __align__(16) __bf16 aBuf[2][TT * KP];   // 2 x 6 KB, swizzled [t][k]
    __shared__ __align__(16) float  oBuf[TT * H_SZ];    // 5.76 KB, [t][h]

    const int b    = blockIdx.x;
    const int tid  = threadIdx.x;
    const int wave = tid >> 6;      // 0..5 -> h-tile
    const int lane = tid & 63;
    const int q    = lane >> 4;     // quad 0..3
    const int n    = lane & 15;
    const int h    = wave * 16 + n; // output column; valid if < 90
    const bool hv  = (h < H_SZ);

    // ---- B fragments (W^T), in registers for the whole kernel ----
    // B[n=h][k]; per-lane j: k = ks*32 + q*8 + j
    bf16x8 bfrag[3][6];
    const int gatebase[3] = {0, 180, 270};   // i, g, o rows of W_ih
    #pragma unroll
    for (int g = 0; g < 3; ++g) {
        const float* wrow = W_ih + (size_t)(gatebase[g] + (hv ? h : 0)) * K_SZ;
        #pragma unroll
        for (int ks = 0; ks < 6; ++ks) {
            bf16x8 f;
            #pragma unroll
            for (int j = 0; j < 8; ++j) {
                int k = ks * 32 + q * 8 + j;
                float v = (hv && k < K_SZ) ? wrow[k] : 0.0f;
                f[j] = (__bf16)v;   // hw RNE cvt
            }
            bfrag[g][ks] = f;
        }
    }

    float bias_i = hv ? (b_ih[h]       + b_hh[h])       : 0.0f;
    float bias_g = hv ? (b_ih[180 + h] + b_hh[180 + h]) : 0.0f;
    float bias_o = hv ? (b_ih[270 + h] + b_hh[270 + h]) : 0.0f;

    const float* xb = x   + (size_t)b * (K_SZ * T_SZ);
    float*       ob = out + (size_t)b * (T_SZ * H_SZ);

    // staging roles: thread -> (k row, t half). 8 contiguous floats along t.
    const int kw   = tid >> 1;      // 0..191
    const int half = tid & 1;       // t half: 0 -> t 0..7, 1 -> t 8..15
    const bool kv  = (kw < K_SZ);

    // zero the K-padding rows (k=180..191) once, in both buffers
    if (!kv) {
        #pragma unroll
        for (int i = 0; i < 8; ++i) {
            int t = half * 8 + i;
            aBuf[0][aidx(t, kw)] = (__bf16)0.0f;
            aBuf[1][aidx(t, kw)] = (__bf16)0.0f;
        }
    }

    // stage tile 0
    if (kv) {
        const f32x4* p = (const f32x4*)(xb + kw * T_SZ + half * 8);
        f32x4 v0 = p[0], v1 = p[1];
        #pragma unroll
        for (int i = 0; i < 4; ++i) aBuf[0][aidx(half * 8 + i,     kw)] = (__bf16)v0[i];
        #pragma unroll
        for (int i = 0; i < 4; ++i) aBuf[0][aidx(half * 8 + 4 + i, kw)] = (__bf16)v1[i];
    }
    __syncthreads();

    int cur = 0;
    #pragma unroll 1
    for (int mt = 0; mt < NT; ++mt) {
        // ---- stage tile mt+1 into the other buffer (overlaps compute) ----
        if (mt + 1 < NT && kv) {
            const f32x4* p = (const f32x4*)(xb + kw * T_SZ + (mt + 1) * TT + half * 8);
            f32x4 v0 = p[0], v1 = p[1];
            __bf16* dst = aBuf[cur ^ 1];
            #pragma unroll
            for (int i = 0; i < 4; ++i) dst[aidx(half * 8 + i,     kw)] = (__bf16)v0[i];
            #pragma unroll
            for (int i = 0; i < 4; ++i) dst[aidx(half * 8 + 4 + i, kw)] = (__bf16)v1[i];
        }

        // ---- MFMA: A from LDS (one ds_read_b128 per ks), B from regs ----
        f32x4 acc0 = {0.f,0.f,0.f,0.f};
        f32x4 acc1 = {0.f,0.f,0.f,0.f};
        f32x4 acc2 = {0.f,0.f,0.f,0.f};
        const __bf16* ab = aBuf[cur];
        #pragma unroll
        for (int ks = 0; ks < 6; ++ks) {
            bf16x8 a = *(const bf16x8*)(ab + n * KP + (((ks * 4 + q) ^ (n & 7)) << 3));
            acc0 = __builtin_amdgcn_mfma_f32_16x16x32_bf16(a, bfrag[0][ks], acc0, 0, 0, 0);
            acc1 = __builtin_amdgcn_mfma_f32_16x16x32_bf16(a, bfrag[1][ks], acc1, 0, 0, 0);
            acc2 = __builtin_amdgcn_mfma_f32_16x16x32_bf16(a, bfrag[2][ks], acc2, 0, 0, 0);
        }

        // ---- epilogue into oBuf (C/D: col=lane&15 -> h, row=q*4+e -> t) ----
        if (hv) {
            #pragma unroll
            for (int e = 0; e < 4; ++e) {
                float gi = acc0[e] + bias_i;
                float gg = acc1[e] + bias_g;
                float go = acc2[e] + bias_o;
                float c  = sigmoidf_(gi) * tanhf_(gg);
                float hh = sigmoidf_(go) * tanhf_(c);
                oBuf[(q * 4 + e) * H_SZ + h] = sigmoidf_(hh);
            }
        }
        __syncthreads();   // oBuf + next-tile aBuf writes visible; aBuf[cur] reads done

        // ---- copy-out: 16 rows x 90 floats = 5760B = 360 x float4, full lines ----
        if (tid < 360) {
            f32x4 v = *(const f32x4*)(oBuf + tid * 4);
            *(f32x4*)(ob + (size_t)mt * (TT * H_SZ) + tid * 4) = v;
        }
        __syncthreads();   // oBuf reads done before next epilogue overwrites
        cur ^= 1;
    }
}

extern "C" void kernel_launch(void* const* d_in, const int* in_sizes, int n_in,
                              void* d_out, int out_size, void* d_ws, size_t ws_size,
                              hipStream_t stream) {
    const float* x    = (const float*)d_in[0];
    const float* W_ih = (const float*)d_in[1];
    // d_in[2] = W_hh: dead (h0 = c0 = 0 at every timestep)
    const float* b_ih = (const float*)d_in[3];
    const float* b_hh = (const float*)d_in[4];
    float* out = (float*)d_out;

    lstm_fused_kernel<<<dim3(B_SZ), dim3(384), 0, stream>>>(x, W_ih, b_ih, b_hh, out);
}

// Round 2
// 647.134 us; speedup vs baseline: 1.2878x; 1.2389x over previous
//
#include <hip/hip_runtime.h>

// Encoder_8718783611479: stateless per-step LSTMCell => one GEMM + elementwise.
//   gates = xt @ W_ih^T (+ b_ih + b_hh), only i,g,o gates live (f * c_prev = 0)
//   out = sigmoid(sigmoid(o_g)*tanh(sigmoid(i_g)*tanh(g_g)))
// xt[b,t,k] = x[b*43200 + k*240 + t]  (K=180 strided, M=t contiguous)
//
// v3: the v1/v2 bottleneck was W-fragment REMATERIALIZATION: VGPR_Count=64 <
// 72 regs of bfrag alone => compiler re-gathered W (144 divergent loads/thread)
// EVERY tile. Fix: (a) prepack kernel writes W in fragment order (bf16,
// lane-contiguous) into d_ws -> main kernel W load = 18 coalesced 16B loads;
// (b) __launch_bounds__(384,3) gives a 170-VGPR budget so bfrag stays
// resident; (c) x staging loads remapped to full-row segments (min line
// count); (d) TC=48 chunks, 1 barrier/chunk (6 vs 30), conflict-free swizzle.

#define B_SZ 2048
#define T_SZ 240
#define K_SZ 180
#define H_SZ 90
#define KP   192   // K padded to 6*32
#define TC   48    // t-chunk (3 MFMA tiles)
#define NC   5     // 240/48
#define TPC  3     // 16-row tiles per chunk

#define WS_W_BYTES 110592           // 3*6*6*64*16 B of bf16 W fragments
#define WS_B_OFF   110592           // then [3][96] f32 fused biases

typedef __bf16 bf16x8 __attribute__((ext_vector_type(8)));
typedef float  f32x4  __attribute__((ext_vector_type(4)));

__device__ __forceinline__ float sigmoidf_(float x) {
    return __builtin_amdgcn_rcpf(1.0f + __expf(-x));
}
__device__ __forceinline__ float tanhf_(float x) {
    return 1.0f - 2.0f * __builtin_amdgcn_rcpf(__expf(2.0f * x) + 1.0f);
}

// 3-bit slot key from t&15; distinguishes t and t^8 so both staging writes
// (t strided) and frag reads (16 consecutive t) spread across all 8 slots.
__device__ __forceinline__ int fsw(int t) {
    return (t & 7) ^ (((t >> 3) & 1) << 2);
}
// swizzled element index into a [TC][KP] bf16 tile (granule = 8 k = 16B)
__device__ __forceinline__ int aidx(int t, int k) {
    int g    = k >> 3;
    int slot = (g & ~7) | ((g & 7) ^ fsw(t & 15));
    return t * KP + (slot << 3) + (k & 7);
}

// ---------------- prepack: W fragments + fused bias into d_ws ----------------
__global__ __launch_bounds__(384) void prepack_kernel(
    const float* __restrict__ W_ih,
    const float* __restrict__ b_ih,
    const float* __restrict__ b_hh,
    void* __restrict__ ws)
{
    __bf16* wp = (__bf16*)ws;
    float*  bp = (float*)((char*)ws + WS_B_OFF);
    const int gb[3] = {0, 180, 270};   // i, g, o row bases in W_ih (4H=360 rows)

    const int bid = blockIdx.x;
    const int tid = threadIdx.x;
    if (bid < 18) {
        const int g  = bid / 6;
        const int ks = bid % 6;
        const int w  = tid >> 6;
        const int l  = tid & 63;
        const int q  = l >> 4;
        const int n  = l & 15;
        const int h  = w * 16 + n;
        bf16x8 f;
        #pragma unroll
        for (int j = 0; j < 8; ++j) {
            int k = ks * 32 + q * 8 + j;
            float v = (h < H_SZ && k < K_SZ) ? W_ih[(size_t)(gb[g] + h) * K_SZ + k] : 0.0f;
            f[j] = (__bf16)v;
        }
        // fragment order: [g][ks][wave][lane] x 16B -> coalesced load in main
        *(bf16x8*)(wp + (size_t)(((g * 6 + ks) * 6 + w) * 64 + l) * 8) = f;
    } else {
        if (tid < 288) {
            int g = tid / 96, hh = tid % 96;
            bp[g * 96 + hh] = (hh < H_SZ) ? (b_ih[gb[g] + hh] + b_hh[gb[g] + hh]) : 0.0f;
        }
    }
}

// ---------------- main kernel ----------------
__device__ __forceinline__ void stage_chunk(
    const float* __restrict__ xb, __bf16* __restrict__ dst, int c, int tid)
{
    // unit u -> (k = u/12, t4 = u%12): lanes walk t4 fastest => each wave-load
    // covers complete 192B line-aligned row segments (minimal line count).
    #pragma unroll
    for (int p = 0; p < 6; ++p) {
        int u = tid + p * 384;
        if (p < 5 || u < 2160) {           // 180 rows * 12 quads = 2160 units
            int k  = u / 12;
            int t4 = u - k * 12;
            const f32x4 v = *(const f32x4*)(xb + k * T_SZ + c * TC + t4 * 4);
            #pragma unroll
            for (int i = 0; i < 4; ++i)
                dst[aidx(t4 * 4 + i, k)] = (__bf16)v[i];
        }
    }
}

__global__ __launch_bounds__(384, 3) void lstm_fused_kernel(
    const float* __restrict__ x,
    const void*  __restrict__ ws,
    float* __restrict__ out)
{
    __shared__ __align__(16) __bf16 aBuf[2][TC * KP];   // 2 x 18 KB, swizzled [t][k]

    const int b    = blockIdx.x;
    const int tid  = threadIdx.x;
    const int wave = tid >> 6;      // 0..5 -> h-tile
    const int lane = tid & 63;
    const int q    = lane >> 4;     // quad 0..3
    const int n    = lane & 15;
    const int h    = wave * 16 + n; // output column; valid if < 90
    const bool hv  = (h < H_SZ);

    // ---- W fragments: 18 coalesced 16B loads from prepacked ws ----
    const bf16x8* wp = (const bf16x8*)ws;
    bf16x8 bfrag[3][6];
    #pragma unroll
    for (int g = 0; g < 3; ++g)
        #pragma unroll
        for (int ks = 0; ks < 6; ++ks)
            bfrag[g][ks] = wp[((g * 6 + ks) * 6 + wave) * 64 + lane];

    const float* bp = (const float*)((const char*)ws + WS_B_OFF);
    const float bias_i = bp[0 * 96 + h];   // h <= 95, padded with zeros
    const float bias_g = bp[1 * 96 + h];
    const float bias_o = bp[2 * 96 + h];

    const float* xb = x   + (size_t)b * (K_SZ * T_SZ);
    float*       ob = out + (size_t)b * (T_SZ * H_SZ);

    // zero the k-padding (k=180..191) of both buffers once
    for (int e = tid; e < 2 * TC * 12; e += 384) {
        int buf = e / (TC * 12);
        int r   = e - buf * (TC * 12);
        int t   = r / 12;
        int k   = K_SZ + (r - (r / 12) * 12);
        aBuf[buf][aidx(t, k)] = (__bf16)0.0f;
    }

    stage_chunk(xb, aBuf[0], 0, tid);
    __syncthreads();

    int cur = 0;
    #pragma unroll 1
    for (int c = 0; c < NC; ++c) {
        if (c + 1 < NC)
            stage_chunk(xb, aBuf[cur ^ 1], c + 1, tid);

        const __bf16* ab = aBuf[cur];
        #pragma unroll
        for (int tt = 0; tt < TPC; ++tt) {
            f32x4 acc0 = {0.f, 0.f, 0.f, 0.f};
            f32x4 acc1 = {0.f, 0.f, 0.f, 0.f};
            f32x4 acc2 = {0.f, 0.f, 0.f, 0.f};
            #pragma unroll
            for (int ks = 0; ks < 6; ++ks) {
                int g    = ks * 4 + q;
                int slot = (g & ~7) | ((g & 7) ^ fsw(n));
                bf16x8 a = *(const bf16x8*)(ab + (tt * 16 + n) * KP + (slot << 3));
                acc0 = __builtin_amdgcn_mfma_f32_16x16x32_bf16(a, bfrag[0][ks], acc0, 0, 0, 0);
                acc1 = __builtin_amdgcn_mfma_f32_16x16x32_bf16(a, bfrag[1][ks], acc1, 0, 0, 0);
                acc2 = __builtin_amdgcn_mfma_f32_16x16x32_bf16(a, bfrag[2][ks], acc2, 0, 0, 0);
            }
            // C/D layout: col = lane&15 -> h, row = q*4+e -> t within tile
            if (hv) {
                const int tg = c * TC + tt * 16 + q * 4;
                #pragma unroll
                for (int e = 0; e < 4; ++e) {
                    float gi = acc0[e] + bias_i;
                    float gg = acc1[e] + bias_g;
                    float go = acc2[e] + bias_o;
                    float cc = sigmoidf_(gi) * tanhf_(gg);
                    float hh = sigmoidf_(go) * tanhf_(cc);
                    ob[(size_t)(tg + e) * H_SZ + h] = sigmoidf_(hh);
                }
            }
        }
        __syncthreads();   // staging of c+1 done; reads of cur done
        cur ^= 1;
    }
}

extern "C" void kernel_launch(void* const* d_in, const int* in_sizes, int n_in,
                              void* d_out, int out_size, void* d_ws, size_t ws_size,
                              hipStream_t stream) {
    const float* x    = (const float*)d_in[0];
    const float* W_ih = (const float*)d_in[1];
    // d_in[2] = W_hh: dead (h0 = c0 = 0 at every timestep)
    const float* b_ih = (const float*)d_in[3];
    const float* b_hh = (const float*)d_in[4];
    float* out = (float*)d_out;

    // needs ~112 KB of workspace for prepacked W + biases
    prepack_kernel<<<dim3(19), dim3(384), 0, stream>>>(W_ih, b_ih, b_hh, d_ws);
    lstm_fused_kernel<<<dim3(B_SZ), dim3(384), 0, stream>>>(x, d_ws, out);
}